// Round 3
// baseline (553.387 us; speedup 1.0000x reference)
//
#include <hip/hip_runtime.h>
#include <cstddef>

#define GG 2048
#define PP 18
#define NNODE (GG*PP)      // 36864
#define EPG 306            // directed edges per graph (17*18)
#define F1 128             // H1*C1
#define F2 256             // H2*C2
#define XP1 132            // padded row stride (f32) for gat1 xl/xr
#define XP2 260            // padded row stride for gat2 xl/xr
#define AS 20              // alpha row stride [d][h][AS]
#define INF 6

typedef unsigned short u16;
typedef __attribute__((ext_vector_type(8))) short short8;   // 8 bf16
typedef __attribute__((ext_vector_type(4))) float f32x4;

__device__ __forceinline__ float lrelu(float v) { return v > 0.f ? v : 0.01f * v; }

__device__ __forceinline__ u16 f2b(float x) {            // fp32 -> bf16 RNE
    union { float f; unsigned u; } c; c.f = x;
    unsigned r = c.u + 0x7FFF + ((c.u >> 16) & 1);
    return (u16)(r >> 16);
}
__device__ __forceinline__ float b2f(u16 v) {
    union { unsigned u; float f; } c; c.u = ((unsigned)v) << 16;
    return c.f;
}

// ================= layer 1: GATv2 (6 -> 4x32) + BN1 stats, one block/graph =================
__global__ __launch_bounds__(256) void gat1_kernel(
    const float* __restrict__ x, const float* __restrict__ eattr,
    const float* __restrict__ W1l, const float* __restrict__ b1l,
    const float* __restrict__ W1r, const float* __restrict__ b1r,
    const float* __restrict__ We1, const float* __restrict__ att1,
    const float* __restrict__ bias1, float* __restrict__ h1,
    float* __restrict__ sum1, float* __restrict__ ss1)
{
    __shared__ float xs[PP*INF];
    __shared__ float wl[INF*F1], wr[INF*F1];
    __shared__ float bl[F1], br[F1], we[F1], att[F1];
    __shared__ float ea[PP][AS];
    __shared__ float xl[PP][XP1], xr[PP][XP1];
    __shared__ float alpha[PP][4][AS];
    const int g = blockIdx.x, tid = threadIdx.x;

    if (tid < PP*INF) xs[tid] = x[g*PP*INF + tid];
    for (int i = tid; i < INF*F1; i += 256) { wl[i] = W1l[i]; wr[i] = W1r[i]; }
    if (tid < F1) { bl[tid]=b1l[tid]; br[tid]=b1r[tid]; we[tid]=We1[tid]; att[tid]=att1[tid]; }
    for (int t = tid; t < EPG; t += 256) {
        int s = t/17, pos = t%17;
        int d = pos + (pos >= s);
        ea[s][d] = eattr[g*EPG + t];
    }
    __syncthreads();
    if (tid < PP) {
        float sum = 0.f;
        for (int s = 0; s < PP; ++s) if (s != tid) sum += ea[s][tid];
        ea[tid][tid] = sum * (1.f/17.f);
    }
    __syncthreads();
    // projections
    for (int o = tid; o < PP*F1; o += 256) {
        int n = o >> 7, j = o & (F1-1);
        float al = bl[j], ar = br[j];
        #pragma unroll
        for (int k = 0; k < INF; ++k) {
            float xv = xs[n*INF + k];
            al = fmaf(xv, wl[k*F1 + j], al);
            ar = fmaf(xv, wr[k*F1 + j], ar);
        }
        xl[n][j] = al; xr[n][j] = ar;
    }
    __syncthreads();
    // alpha: slot = d*32 + h*8 + q ; thread hoists xr/we/att quad, streams xl
    for (int slot = tid; slot < PP*32; slot += 256) {
        const int d = slot >> 5, h = (slot >> 3) & 3, q = slot & 7;
        const int c0 = h*32 + q*4;
        const float4 xr4 = *(const float4*)&xr[d][c0];
        const float4 we4 = *(const float4*)&we[c0];
        const float4 at4 = *(const float4*)&att[c0];
        float p[PP];
        #pragma unroll
        for (int s = 0; s < PP; ++s) {
            float e = ea[s][d];
            float4 x4 = *(const float4*)&xl[s][c0];
            float v0 = lrelu(fmaf(e, we4.x, xr4.x) + x4.x);
            float v1 = lrelu(fmaf(e, we4.y, xr4.y) + x4.y);
            float v2 = lrelu(fmaf(e, we4.z, xr4.z) + x4.z);
            float v3 = lrelu(fmaf(e, we4.w, xr4.w) + x4.w);
            p[s] = (v0*at4.x + v1*at4.y) + (v2*at4.z + v3*at4.w);
        }
        #pragma unroll
        for (int s = 0; s < PP; ++s) {
            float v = p[s];
            v += __shfl_xor(v, 1); v += __shfl_xor(v, 2); v += __shfl_xor(v, 4);
            p[s] = v;
        }
        if (q == 0) {
            #pragma unroll
            for (int s = 0; s < PP; ++s) alpha[d][h][s] = p[s];
        }
    }
    __syncthreads();
    if (tid < PP*4) {
        const int d = tid >> 2, h = tid & 3;
        float* a = alpha[d][h];
        float m = -1e30f;
        for (int s = 0; s < PP; ++s) m = fmaxf(m, a[s]);
        float sum = 0.f;
        for (int s = 0; s < PP; ++s) sum += __expf(a[s] - m);
        float inv = 1.f/(sum + 1e-16f);
        for (int s = 0; s < PP; ++s) a[s] = __expf(a[s] - m) * inv;
    }
    __syncthreads();
    // PV + write + local BN stats ; slot = d*32 + j4 (j4 = tid&31 constant/thread)
    float4 s_loc = {0,0,0,0}, q_loc = {0,0,0,0};
    for (int slot = tid; slot < PP*32; slot += 256) {
        const int d = slot >> 5, j4 = slot & 31, h = j4 >> 3, c0 = j4*4;
        float4 acc = *(const float4*)&bias1[c0];
        #pragma unroll
        for (int s4 = 0; s4 < 4; ++s4) {
            float4 a4 = *(const float4*)&alpha[d][h][s4*4];
            #pragma unroll
            for (int i = 0; i < 4; ++i) {
                float4 x4 = *(const float4*)&xl[s4*4 + i][c0];
                float av = (i==0)?a4.x:(i==1)?a4.y:(i==2)?a4.z:a4.w;
                acc.x = fmaf(av, x4.x, acc.x); acc.y = fmaf(av, x4.y, acc.y);
                acc.z = fmaf(av, x4.z, acc.z); acc.w = fmaf(av, x4.w, acc.w);
            }
        }
        {
            float a16 = alpha[d][h][16], a17 = alpha[d][h][17];
            float4 x16 = *(const float4*)&xl[16][c0];
            float4 x17 = *(const float4*)&xl[17][c0];
            acc.x = fmaf(a16, x16.x, fmaf(a17, x17.x, acc.x));
            acc.y = fmaf(a16, x16.y, fmaf(a17, x17.y, acc.y));
            acc.z = fmaf(a16, x16.z, fmaf(a17, x17.z, acc.z));
            acc.w = fmaf(a16, x16.w, fmaf(a17, x17.w, acc.w));
        }
        *(float4*)&h1[(size_t)g*(PP*F1) + d*F1 + c0] = acc;
        s_loc.x += acc.x; s_loc.y += acc.y; s_loc.z += acc.z; s_loc.w += acc.w;
        q_loc.x = fmaf(acc.x, acc.x, q_loc.x); q_loc.y = fmaf(acc.y, acc.y, q_loc.y);
        q_loc.z = fmaf(acc.z, acc.z, q_loc.z); q_loc.w = fmaf(acc.w, acc.w, q_loc.w);
    }
    __syncthreads();                       // xl/alpha reads done
    float4* sbuf = (float4*)&xr[0][0];     // reuse xr (2376 f32 >= 512 f32x4)
    sbuf[tid] = s_loc; sbuf[256 + tid] = q_loc;
    __syncthreads();
    if (tid < 32) {                        // 8 partners share j4 = tid
        float4 S = {0,0,0,0}, Q = {0,0,0,0};
        #pragma unroll
        for (int m = 0; m < 8; ++m) {
            float4 a = sbuf[tid + 32*m], b = sbuf[256 + tid + 32*m];
            S.x+=a.x; S.y+=a.y; S.z+=a.z; S.w+=a.w;
            Q.x+=b.x; Q.y+=b.y; Q.z+=b.z; Q.w+=b.w;
        }
        atomicAdd(&sum1[tid*4+0], S.x); atomicAdd(&sum1[tid*4+1], S.y);
        atomicAdd(&sum1[tid*4+2], S.z); atomicAdd(&sum1[tid*4+3], S.w);
        atomicAdd(&ss1[tid*4+0], Q.x);  atomicAdd(&ss1[tid*4+1], Q.y);
        atomicAdd(&ss1[tid*4+2], Q.z);  atomicAdd(&ss1[tid*4+3], Q.w);
    }
}

// ================= BN finalize =================
__global__ void bnfin(const float* __restrict__ sum, const float* __restrict__ ss,
                      const float* __restrict__ gamma, const float* __restrict__ beta,
                      float* __restrict__ sc, float* __restrict__ sh, int C, float invN)
{
    int c = threadIdx.x + blockIdx.x*blockDim.x;
    if (c < C) {
        float mu = sum[c]*invN;
        float var = ss[c]*invN - mu*mu;
        float s = gamma[c]*rsqrtf(var + 1e-5f);
        sc[c] = s;
        sh[c] = beta[c] - mu*s;
    }
}

// ================= prep: W2 -> bf16 transposed, bias concat, zero stats =================
__global__ void prep_w(const float* __restrict__ W2l, const float* __restrict__ W2r,
                       const float* __restrict__ b2l, const float* __restrict__ b2r,
                       u16* __restrict__ wbt, float* __restrict__ biascat,
                       float* __restrict__ st)
{
    int t = blockIdx.x*blockDim.x + threadIdx.x;
    if (t < 1536) st[t] = 0.f;
    if (t < 512*128) {
        int c = t >> 7, k = t & 127;
        float v = (c < 256) ? W2l[k*256 + c] : W2r[k*256 + (c-256)];
        wbt[t] = f2b(v);           // wbt[c][k]
    } else if (t < 512*128 + 512) {
        int c = t - 512*128;
        biascat[c] = (c < 256) ? b2l[c] : b2r[c-256];
    }
}

// ================= layer-2 projection GEMM (bn1+lrelu fused into A-stage) =================
__global__ __launch_bounds__(256) void gemm2_kernel(
    const float* __restrict__ h1, const float* __restrict__ sc1, const float* __restrict__ sh1,
    const u16* __restrict__ wbt, const float* __restrict__ biascat, u16* __restrict__ xlr)
{
    __shared__ u16 As[64*128];
    __shared__ u16 Bs[64*128];
    __shared__ float scs[F1], shs[F1];
    const int b = blockIdx.x;
    const int bm = b >> 3, bn = b & 7;
    const int r0 = bm*64, c0 = bn*64;
    const int tid = threadIdx.x;

    if (tid < F1) { scs[tid] = sc1[tid]; shs[tid] = sh1[tid]; }
    __syncthreads();
    for (int i = tid*8; i < 64*128; i += 256*8) {
        int r = i >> 7, c = i & 127;
        float4 v0 = *(const float4*)&h1[(size_t)(r0+r)*128 + c];
        float4 v1 = *(const float4*)&h1[(size_t)(r0+r)*128 + c + 4];
        short8 a;
        a[0] = (short)f2b(lrelu(fmaf(scs[c+0], v0.x, shs[c+0])));
        a[1] = (short)f2b(lrelu(fmaf(scs[c+1], v0.y, shs[c+1])));
        a[2] = (short)f2b(lrelu(fmaf(scs[c+2], v0.z, shs[c+2])));
        a[3] = (short)f2b(lrelu(fmaf(scs[c+3], v0.w, shs[c+3])));
        a[4] = (short)f2b(lrelu(fmaf(scs[c+4], v1.x, shs[c+4])));
        a[5] = (short)f2b(lrelu(fmaf(scs[c+5], v1.y, shs[c+5])));
        a[6] = (short)f2b(lrelu(fmaf(scs[c+6], v1.z, shs[c+6])));
        a[7] = (short)f2b(lrelu(fmaf(scs[c+7], v1.w, shs[c+7])));
        int idx = i ^ ((r & 7) << 3);
        *reinterpret_cast<short8*>(&As[idx]) = a;
        *reinterpret_cast<short8*>(&Bs[idx]) =
            *reinterpret_cast<const short8*>(&wbt[(size_t)(c0+r)*128 + c]);
    }
    __syncthreads();

    const int w = tid >> 6, l = tid & 63;
    const int lr = l & 15, lk = (l >> 4) * 8;
    const int ar = w*16 + lr;
    f32x4 acc[4] = {f32x4{0,0,0,0}, f32x4{0,0,0,0}, f32x4{0,0,0,0}, f32x4{0,0,0,0}};

    #pragma unroll
    for (int kk = 0; kk < 4; ++kk) {
        int k0 = kk*32 + lk;
        short8 a = *reinterpret_cast<const short8*>(&As[(ar*128 + k0) ^ ((ar & 7) << 3)]);
        #pragma unroll
        for (int n = 0; n < 4; ++n) {
            int br = n*16 + lr;
            short8 bf = *reinterpret_cast<const short8*>(&Bs[(br*128 + k0) ^ ((br & 7) << 3)]);
            acc[n] = __builtin_amdgcn_mfma_f32_16x16x32_bf16(a, bf, acc[n], 0, 0, 0);
        }
    }
    const int rbase = r0 + w*16 + (l >> 4)*4;
    #pragma unroll
    for (int n = 0; n < 4; ++n) {
        int C = c0 + n*16 + lr;
        float bv = biascat[C];
        #pragma unroll
        for (int j = 0; j < 4; ++j) {
            xlr[(size_t)(rbase + j)*512 + C] = f2b(acc[n][j] + bv);
        }
    }
}

// ================= layer 2 attention + BN2 stats, one block/graph =================
__global__ __launch_bounds__(256) void gat2_attn(
    const u16* __restrict__ xlr, const float* __restrict__ eattr,
    const float* __restrict__ We2, const float* __restrict__ att2,
    const float* __restrict__ bias2, float* __restrict__ h2,
    float* __restrict__ sum2, float* __restrict__ ss2)
{
    __shared__ float xl[PP][XP2], xr[PP][XP2];
    __shared__ float ea[PP][AS];
    __shared__ float alpha[PP][4][AS];
    __shared__ float we[F2], att[F2];
    const int g = blockIdx.x, tid = threadIdx.x;

    if (tid < F2) { we[tid] = We2[tid]; att[tid] = att2[tid]; }
    for (int i4 = tid; i4 < PP*128; i4 += 256) {
        int n = i4 >> 7, j = (i4 & 127) * 4;
        ushort4 v = *reinterpret_cast<const ushort4*>(&xlr[(size_t)(g*PP + n)*512 + j]);
        float* dst = (j < 256) ? &xl[n][j] : &xr[n][j - 256];
        dst[0] = b2f(v.x); dst[1] = b2f(v.y); dst[2] = b2f(v.z); dst[3] = b2f(v.w);
    }
    for (int t = tid; t < EPG; t += 256) {
        int s = t/17, pos = t%17;
        int d = pos + (pos >= s);
        ea[s][d] = eattr[g*EPG + t];
    }
    __syncthreads();
    if (tid < PP) {
        float sum = 0.f;
        for (int s = 0; s < PP; ++s) if (s != tid) sum += ea[s][tid];
        ea[tid][tid] = sum * (1.f/17.f);
    }
    __syncthreads();
    // alpha: slot = d*64 + h*16 + q
    for (int slot = tid; slot < PP*64; slot += 256) {
        const int d = slot >> 6, h = (slot >> 4) & 3, q = slot & 15;
        const int c0 = h*64 + q*4;
        const float4 xr4 = *(const float4*)&xr[d][c0];
        const float4 we4 = *(const float4*)&we[c0];
        const float4 at4 = *(const float4*)&att[c0];
        float p[PP];
        #pragma unroll
        for (int s = 0; s < PP; ++s) {
            float e = ea[s][d];
            float4 x4 = *(const float4*)&xl[s][c0];
            float v0 = lrelu(fmaf(e, we4.x, xr4.x) + x4.x);
            float v1 = lrelu(fmaf(e, we4.y, xr4.y) + x4.y);
            float v2 = lrelu(fmaf(e, we4.z, xr4.z) + x4.z);
            float v3 = lrelu(fmaf(e, we4.w, xr4.w) + x4.w);
            p[s] = (v0*at4.x + v1*at4.y) + (v2*at4.z + v3*at4.w);
        }
        #pragma unroll
        for (int s = 0; s < PP; ++s) {
            float v = p[s];
            v += __shfl_xor(v, 1); v += __shfl_xor(v, 2);
            v += __shfl_xor(v, 4); v += __shfl_xor(v, 8);
            p[s] = v;
        }
        if (q == 0) {
            #pragma unroll
            for (int s = 0; s < PP; ++s) alpha[d][h][s] = p[s];
        }
    }
    __syncthreads();
    if (tid < PP*4) {
        const int d = tid >> 2, h = tid & 3;
        float* a = alpha[d][h];
        float m = -1e30f;
        for (int s = 0; s < PP; ++s) m = fmaxf(m, a[s]);
        float sum = 0.f;
        for (int s = 0; s < PP; ++s) sum += __expf(a[s] - m);
        float inv = 1.f/(sum + 1e-16f);
        for (int s = 0; s < PP; ++s) a[s] = __expf(a[s] - m) * inv;
    }
    __syncthreads();
    // PV + write + local BN2 stats ; j4 = tid&63 constant/thread
    float4 s_loc = {0,0,0,0}, q_loc = {0,0,0,0};
    for (int slot = tid; slot < PP*64; slot += 256) {
        const int d = slot >> 6, j4 = slot & 63, h = j4 >> 4, c0 = j4*4;
        float4 acc = *(const float4*)&bias2[c0];
        #pragma unroll
        for (int s4 = 0; s4 < 4; ++s4) {
            float4 a4 = *(const float4*)&alpha[d][h][s4*4];
            #pragma unroll
            for (int i = 0; i < 4; ++i) {
                float4 x4 = *(const float4*)&xl[s4*4 + i][c0];
                float av = (i==0)?a4.x:(i==1)?a4.y:(i==2)?a4.z:a4.w;
                acc.x = fmaf(av, x4.x, acc.x); acc.y = fmaf(av, x4.y, acc.y);
                acc.z = fmaf(av, x4.z, acc.z); acc.w = fmaf(av, x4.w, acc.w);
            }
        }
        {
            float a16 = alpha[d][h][16], a17 = alpha[d][h][17];
            float4 x16 = *(const float4*)&xl[16][c0];
            float4 x17 = *(const float4*)&xl[17][c0];
            acc.x = fmaf(a16, x16.x, fmaf(a17, x17.x, acc.x));
            acc.y = fmaf(a16, x16.y, fmaf(a17, x17.y, acc.y));
            acc.z = fmaf(a16, x16.z, fmaf(a17, x17.z, acc.z));
            acc.w = fmaf(a16, x16.w, fmaf(a17, x17.w, acc.w));
        }
        *(float4*)&h2[(size_t)g*(PP*F2) + d*F2 + c0] = acc;
        s_loc.x += acc.x; s_loc.y += acc.y; s_loc.z += acc.z; s_loc.w += acc.w;
        q_loc.x = fmaf(acc.x, acc.x, q_loc.x); q_loc.y = fmaf(acc.y, acc.y, q_loc.y);
        q_loc.z = fmaf(acc.z, acc.z, q_loc.z); q_loc.w = fmaf(acc.w, acc.w, q_loc.w);
    }
    __syncthreads();
    float4* sbuf = (float4*)&xr[0][0];     // reuse xr (4680 f32 >= 512 f32x4)
    sbuf[tid] = s_loc; sbuf[256 + tid] = q_loc;
    __syncthreads();
    if (tid < 64) {                        // 4 partners share j4 = tid
        float4 S = {0,0,0,0}, Q = {0,0,0,0};
        #pragma unroll
        for (int m = 0; m < 4; ++m) {
            float4 a = sbuf[tid + 64*m], b = sbuf[256 + tid + 64*m];
            S.x+=a.x; S.y+=a.y; S.z+=a.z; S.w+=a.w;
            Q.x+=b.x; Q.y+=b.y; Q.z+=b.z; Q.w+=b.w;
        }
        atomicAdd(&sum2[tid*4+0], S.x); atomicAdd(&sum2[tid*4+1], S.y);
        atomicAdd(&sum2[tid*4+2], S.z); atomicAdd(&sum2[tid*4+3], S.w);
        atomicAdd(&ss2[tid*4+0], Q.x);  atomicAdd(&ss2[tid*4+1], Q.y);
        atomicAdd(&ss2[tid*4+2], Q.z);  atomicAdd(&ss2[tid*4+3], Q.w);
    }
}

// ================= BN2+lrelu + mean-pool + MLP head, 8 graphs/block =================
__global__ __launch_bounds__(256) void mlp_kernel(
    const float* __restrict__ h2, const float* __restrict__ sc2, const float* __restrict__ sh2,
    const float* __restrict__ Wfc1, const float* __restrict__ bfc1,
    const float* __restrict__ Wfc2, const float* __restrict__ bfc2,
    const float* __restrict__ Wfc3, const float* __restrict__ bfc3,
    float* __restrict__ out)
{
    __shared__ float pooled[8][F2];
    __shared__ float y1[8][512];
    __shared__ float y2[8][128];
    const int g0 = blockIdx.x * 8, tid = threadIdx.x;
    const float scv = sc2[tid], shv = sh2[tid];
    #pragma unroll
    for (int gi = 0; gi < 8; ++gi) {
        float s = 0.f;
        for (int n = 0; n < PP; ++n) {
            float v = fmaf(scv, h2[((size_t)(g0+gi)*PP + n)*F2 + tid], shv);
            s += lrelu(v);
        }
        pooled[gi][tid] = s * (1.f/18.f);
    }
    __syncthreads();
    #pragma unroll
    for (int jo = 0; jo < 2; ++jo) {
        int j = tid + jo*256;
        float acc[8];
        float bv = bfc1[j];
        #pragma unroll
        for (int gi = 0; gi < 8; ++gi) acc[gi] = bv;
        for (int k = 0; k < F2; ++k) {
            float w = Wfc1[k*512 + j];
            #pragma unroll
            for (int gi = 0; gi < 8; ++gi) acc[gi] = fmaf(pooled[gi][k], w, acc[gi]);
        }
        #pragma unroll
        for (int gi = 0; gi < 8; ++gi) y1[gi][j] = lrelu(acc[gi]);
    }
    __syncthreads();
    {
        int j = tid & 127, kh = tid >> 7;
        float acc[8] = {0,0,0,0,0,0,0,0};
        for (int k = kh*256; k < kh*256 + 256; ++k) {
            float w = Wfc2[k*128 + j];
            #pragma unroll
            for (int gi = 0; gi < 8; ++gi) acc[gi] = fmaf(y1[gi][k], w, acc[gi]);
        }
        if (kh == 1) {
            #pragma unroll
            for (int gi = 0; gi < 8; ++gi) pooled[gi][j] = acc[gi];
        }
        __syncthreads();
        if (kh == 0) {
            float w3 = Wfc3[j], bv = bfc2[j];
            #pragma unroll
            for (int gi = 0; gi < 8; ++gi)
                y2[gi][j] = lrelu(acc[gi] + pooled[gi][j] + bv) * w3;
        }
    }
    __syncthreads();
    {
        int gi = tid >> 5, l = tid & 31;
        float p = y2[gi][l] + y2[gi][l+32] + y2[gi][l+64] + y2[gi][l+96];
        p += __shfl_xor(p, 1); p += __shfl_xor(p, 2); p += __shfl_xor(p, 4);
        p += __shfl_xor(p, 8); p += __shfl_xor(p, 16);
        if (l == 0) out[g0 + gi] = p + bfc3[0];
    }
}

extern "C" void kernel_launch(void* const* d_in, const int* in_sizes, int n_in,
                              void* d_out, int out_size, void* d_ws, size_t ws_size,
                              hipStream_t stream)
{
    const float* x     = (const float*)d_in[0];
    const float* eattr = (const float*)d_in[1];
    const float* W1l   = (const float*)d_in[4];
    const float* b1l   = (const float*)d_in[5];
    const float* W1r   = (const float*)d_in[6];
    const float* b1r   = (const float*)d_in[7];
    const float* We1   = (const float*)d_in[8];
    const float* att1  = (const float*)d_in[9];
    const float* bias1 = (const float*)d_in[10];
    const float* W2l   = (const float*)d_in[11];
    const float* b2l   = (const float*)d_in[12];
    const float* W2r   = (const float*)d_in[13];
    const float* b2r   = (const float*)d_in[14];
    const float* We2   = (const float*)d_in[15];
    const float* att2  = (const float*)d_in[16];
    const float* bias2 = (const float*)d_in[17];
    const float* g1    = (const float*)d_in[18];
    const float* be1   = (const float*)d_in[19];
    const float* g2    = (const float*)d_in[20];
    const float* be2   = (const float*)d_in[21];
    const float* Wfc1  = (const float*)d_in[22];
    const float* bfc1  = (const float*)d_in[23];
    const float* Wfc2  = (const float*)d_in[24];
    const float* bfc2  = (const float*)d_in[25];
    const float* Wfc3  = (const float*)d_in[26];
    const float* bfc3  = (const float*)d_in[27];
    float* out = (float*)d_out;

    float* ws = (float*)d_ws;
    float* h1 = ws;                                  // NNODE*128 f32
    float* h2 = h1 + (size_t)NNODE*F1;               // NNODE*256 f32
    float* st = h2 + (size_t)NNODE*F2;               // 1536 f32 stats
    float* biascat = st + 1536;                      // 512 f32
    u16* xlr = (u16*)(biascat + 512);                // NNODE*512 bf16
    u16* wbt = xlr + (size_t)NNODE*F2*2;             // 512*128 bf16

    float* sum1 = st,     *ss1 = st+128, *sc1 = st+256,  *sh1 = st+384;
    float* sum2 = st+512, *ss2 = st+768, *sc2 = st+1024, *sh2 = st+1280;

    prep_w<<<259, 256, 0, stream>>>(W2l, W2r, b2l, b2r, wbt, biascat, st);
    gat1_kernel<<<GG, 256, 0, stream>>>(x, eattr, W1l, b1l, W1r, b1r, We1, att1, bias1, h1, sum1, ss1);
    bnfin<<<1, 128, 0, stream>>>(sum1, ss1, g1, be1, sc1, sh1, F1, 1.f/NNODE);
    gemm2_kernel<<<(NNODE/64)*8, 256, 0, stream>>>(h1, sc1, sh1, wbt, biascat, xlr);
    gat2_attn<<<GG, 256, 0, stream>>>(xlr, eattr, We2, att2, bias2, h2, sum2, ss2);
    bnfin<<<1, 256, 0, stream>>>(sum2, ss2, g2, be2, sc2, sh2, F2, 1.f/NNODE);
    mlp_kernel<<<GG/8, 256, 0, stream>>>(h2, sc2, sh2, Wfc1, bfc1, Wfc2, bfc2, Wfc3, bfc3, out);
}

// Round 4
// 278.905 us; speedup vs baseline: 1.9841x; 1.9841x over previous
//
#include <hip/hip_runtime.h>
#include <cstddef>

#define GG 2048
#define PP 18
#define NNODE (GG*PP)      // 36864
#define EPG 306            // directed edges per graph (17*18)
#define F1 128             // H1*C1
#define F2 256             // H2*C2
#define H1n 4
#define C1n 32
#define H2n 4
#define C2n 64
#define INF 6

typedef unsigned short u16;
typedef __attribute__((ext_vector_type(8))) short short8;   // 8 bf16
typedef __attribute__((ext_vector_type(4))) float f32x4;

__device__ __forceinline__ float lrelu(float v) { return v > 0.f ? v : 0.01f * v; }

__device__ __forceinline__ u16 f2b(float x) {            // fp32 -> bf16 RNE
    union { float f; unsigned u; } c; c.f = x;
    unsigned r = c.u + 0x7FFF + ((c.u >> 16) & 1);
    return (u16)(r >> 16);
}
__device__ __forceinline__ float b2f(u16 v) {
    union { unsigned u; float f; } c; c.u = ((unsigned)v) << 16;
    return c.f;
}

// ================= layer 1: GATv2 (6 -> 4x32) + BN1 stats, one block/graph =================
// R2-proven compute pattern (scalar rotated LDS reads); BN stats fused in epilogue.
__global__ __launch_bounds__(256) void gat1_kernel(
    const float* __restrict__ x, const float* __restrict__ eattr,
    const float* __restrict__ W1l, const float* __restrict__ b1l,
    const float* __restrict__ W1r, const float* __restrict__ b1r,
    const float* __restrict__ We1, const float* __restrict__ att1,
    const float* __restrict__ bias1, float* __restrict__ h1,
    float* __restrict__ sum1, float* __restrict__ ss1)
{
    __shared__ float xs[PP*INF];
    __shared__ float wl[INF*F1], wr[INF*F1];
    __shared__ float bl[F1], br[F1], we[F1], att[F1];
    __shared__ float ea[PP*PP];            // ea[s*18+d]
    __shared__ float xl[PP*F1], xr[PP*F1];
    __shared__ float alpha[PP*PP*H1n];     // [d][s][h]
    const int g = blockIdx.x, tid = threadIdx.x;

    if (tid < PP*INF) xs[tid] = x[g*PP*INF + tid];
    for (int i = tid; i < INF*F1; i += 256) { wl[i] = W1l[i]; wr[i] = W1r[i]; }
    if (tid < F1) { bl[tid]=b1l[tid]; br[tid]=b1r[tid]; we[tid]=We1[tid]; att[tid]=att1[tid]; }
    for (int t = tid; t < EPG; t += 256) {
        int s = t/17, pos = t%17;
        int d = pos + (pos >= s);
        ea[s*PP + d] = eattr[g*EPG + t];
    }
    __syncthreads();
    if (tid < PP) {   // self-loop attr = mean of incoming
        float sum = 0.f;
        for (int s = 0; s < PP; ++s) if (s != tid) sum += ea[s*PP + tid];
        ea[tid*PP + tid] = sum * (1.f/17.f);
    }
    __syncthreads();
    for (int o = tid; o < PP*F1; o += 256) {
        int n = o >> 7, j = o & (F1-1);
        float al = bl[j], ar = br[j];
        #pragma unroll
        for (int k = 0; k < INF; ++k) {
            float xv = xs[n*INF + k];
            al = fmaf(xv, wl[k*F1 + j], al);
            ar = fmaf(xv, wr[k*F1 + j], ar);
        }
        xl[o] = al; xr[o] = ar;
    }
    __syncthreads();
    for (int t = tid; t < PP*PP*H1n; t += 256) {
        int h = t & 3, s = (t >> 2) % PP, d = t / (PP*H1n);
        float eav = ea[s*PP + d];
        int j0 = h*C1n;
        float acc = 0.f;
        for (int cc = 0; cc < C1n; ++cc) {
            int c = (cc + tid) & (C1n-1);   // rotate to spread LDS banks
            float v = lrelu(xl[s*F1 + j0 + c] + xr[d*F1 + j0 + c] + eav*we[j0 + c]);
            acc = fmaf(v, att[j0 + c], acc);
        }
        alpha[t] = acc;
    }
    __syncthreads();
    if (tid < PP*H1n) {
        int d = tid >> 2, h = tid & 3;
        int base = d*(PP*H1n) + h;
        float m = -1e30f;
        for (int s = 0; s < PP; ++s) m = fmaxf(m, alpha[base + s*H1n]);
        float sum = 0.f;
        for (int s = 0; s < PP; ++s) sum += __expf(alpha[base + s*H1n] - m);
        float inv = 1.f/(sum + 1e-16f);
        for (int s = 0; s < PP; ++s)
            alpha[base + s*H1n] = __expf(alpha[base + s*H1n] - m) * inv;
    }
    __syncthreads();
    // PV + write + local BN stats (j = tid&127 fixed per thread; d = (o>>7))
    float s_loc = 0.f, q_loc = 0.f;
    for (int o = tid; o < PP*F1; o += 256) {
        int d = o >> 7, j = o & (F1-1), h = j >> 5;
        float acc = bias1[j];
        for (int s = 0; s < PP; ++s)
            acc = fmaf(alpha[d*(PP*H1n) + s*H1n + h], xl[s*F1 + j], acc);
        h1[(size_t)g*(PP*F1) + o] = acc;
        s_loc += acc;
        q_loc = fmaf(acc, acc, q_loc);
    }
    __syncthreads();                       // all xl/alpha reads done; wl/wr free
    wl[tid] = s_loc;
    wr[tid] = q_loc;
    __syncthreads();
    if (tid < F1) {
        atomicAdd(&sum1[tid], wl[tid] + wl[tid + 128]);
        atomicAdd(&ss1[tid],  wr[tid] + wr[tid + 128]);
    }
}

// ================= BN finalize =================
__global__ void bnfin(const float* __restrict__ sum, const float* __restrict__ ss,
                      const float* __restrict__ gamma, const float* __restrict__ beta,
                      float* __restrict__ sc, float* __restrict__ sh, int C, float invN)
{
    int c = threadIdx.x + blockIdx.x*blockDim.x;
    if (c < C) {
        float mu = sum[c]*invN;
        float var = ss[c]*invN - mu*mu;
        float s = gamma[c]*rsqrtf(var + 1e-5f);
        sc[c] = s;
        sh[c] = beta[c] - mu*s;
    }
}

// ================= prep: W2 -> bf16 transposed, bias concat, zero stats =================
__global__ void prep_w(const float* __restrict__ W2l, const float* __restrict__ W2r,
                       const float* __restrict__ b2l, const float* __restrict__ b2r,
                       u16* __restrict__ wbt, float* __restrict__ biascat,
                       float* __restrict__ st)
{
    int t = blockIdx.x*blockDim.x + threadIdx.x;
    if (t < 1536) st[t] = 0.f;
    if (t < 512*128) {
        int c = t >> 7, k = t & 127;
        float v = (c < 256) ? W2l[k*256 + c] : W2r[k*256 + (c-256)];
        wbt[t] = f2b(v);           // wbt[c][k]
    } else if (t < 512*128 + 512) {
        int c = t - 512*128;
        biascat[c] = (c < 256) ? b2l[c] : b2r[c-256];
    }
}

// ================= layer-2 projection GEMM (bn1+lrelu fused into A-stage) =================
__global__ __launch_bounds__(256) void gemm2_kernel(
    const float* __restrict__ h1, const float* __restrict__ sc1, const float* __restrict__ sh1,
    const u16* __restrict__ wbt, const float* __restrict__ biascat, u16* __restrict__ xlr)
{
    __shared__ u16 As[64*128];
    __shared__ u16 Bs[64*128];
    __shared__ float scs[F1], shs[F1];
    const int b = blockIdx.x;
    const int bm = b >> 3, bn = b & 7;
    const int r0 = bm*64, c0 = bn*64;
    const int tid = threadIdx.x;

    if (tid < F1) { scs[tid] = sc1[tid]; shs[tid] = sh1[tid]; }
    __syncthreads();
    for (int i = tid*8; i < 64*128; i += 256*8) {
        int r = i >> 7, c = i & 127;
        float4 v0 = *(const float4*)&h1[(size_t)(r0+r)*128 + c];
        float4 v1 = *(const float4*)&h1[(size_t)(r0+r)*128 + c + 4];
        short8 a;
        a[0] = (short)f2b(lrelu(fmaf(scs[c+0], v0.x, shs[c+0])));
        a[1] = (short)f2b(lrelu(fmaf(scs[c+1], v0.y, shs[c+1])));
        a[2] = (short)f2b(lrelu(fmaf(scs[c+2], v0.z, shs[c+2])));
        a[3] = (short)f2b(lrelu(fmaf(scs[c+3], v0.w, shs[c+3])));
        a[4] = (short)f2b(lrelu(fmaf(scs[c+4], v1.x, shs[c+4])));
        a[5] = (short)f2b(lrelu(fmaf(scs[c+5], v1.y, shs[c+5])));
        a[6] = (short)f2b(lrelu(fmaf(scs[c+6], v1.z, shs[c+6])));
        a[7] = (short)f2b(lrelu(fmaf(scs[c+7], v1.w, shs[c+7])));
        int idx = i ^ ((r & 7) << 3);
        *reinterpret_cast<short8*>(&As[idx]) = a;
        *reinterpret_cast<short8*>(&Bs[idx]) =
            *reinterpret_cast<const short8*>(&wbt[(size_t)(c0+r)*128 + c]);
    }
    __syncthreads();

    const int w = tid >> 6, l = tid & 63;
    const int lr = l & 15, lk = (l >> 4) * 8;
    const int ar = w*16 + lr;
    f32x4 acc[4] = {f32x4{0,0,0,0}, f32x4{0,0,0,0}, f32x4{0,0,0,0}, f32x4{0,0,0,0}};

    #pragma unroll
    for (int kk = 0; kk < 4; ++kk) {
        int k0 = kk*32 + lk;
        short8 a = *reinterpret_cast<const short8*>(&As[(ar*128 + k0) ^ ((ar & 7) << 3)]);
        #pragma unroll
        for (int n = 0; n < 4; ++n) {
            int br = n*16 + lr;
            short8 bf = *reinterpret_cast<const short8*>(&Bs[(br*128 + k0) ^ ((br & 7) << 3)]);
            acc[n] = __builtin_amdgcn_mfma_f32_16x16x32_bf16(a, bf, acc[n], 0, 0, 0);
        }
    }
    const int rbase = r0 + w*16 + (l >> 4)*4;
    #pragma unroll
    for (int n = 0; n < 4; ++n) {
        int C = c0 + n*16 + lr;
        float bv = biascat[C];
        #pragma unroll
        for (int j = 0; j < 4; ++j) {
            xlr[(size_t)(rbase + j)*512 + C] = f2b(acc[n][j] + bv);
        }
    }
}

// ================= layer 2 attention + BN2 stats, one block/graph =================
// R2-proven compute pattern; BN2 stats fused (thread tid owns column tid).
__global__ __launch_bounds__(256) void gat2_attn(
    const u16* __restrict__ xlr, const float* __restrict__ eattr,
    const float* __restrict__ We2, const float* __restrict__ att2,
    const float* __restrict__ bias2, float* __restrict__ h2,
    float* __restrict__ sum2, float* __restrict__ ss2)
{
    __shared__ float xl[PP*F2], xr[PP*F2];
    __shared__ float ea[PP*PP];
    __shared__ float alpha[PP*PP*H2n];
    __shared__ float we[F2], att[F2];
    const int g = blockIdx.x, tid = threadIdx.x;

    if (tid < F2) { we[tid] = We2[tid]; att[tid] = att2[tid]; }
    for (int i4 = tid; i4 < PP*128; i4 += 256) {     // 18*512 elems in quads
        int i = i4*4, n = i >> 9, j = i & 511;
        ushort4 v = *reinterpret_cast<const ushort4*>(&xlr[(size_t)(g*PP + n)*512 + j]);
        float* dst = (j < 256) ? &xl[n*F2 + j] : &xr[n*F2 + j - 256];
        dst[0] = b2f(v.x); dst[1] = b2f(v.y); dst[2] = b2f(v.z); dst[3] = b2f(v.w);
    }
    for (int t = tid; t < EPG; t += 256) {
        int s = t/17, pos = t%17;
        int d = pos + (pos >= s);
        ea[s*PP + d] = eattr[g*EPG + t];
    }
    __syncthreads();
    if (tid < PP) {
        float sum = 0.f;
        for (int s = 0; s < PP; ++s) if (s != tid) sum += ea[s*PP + tid];
        ea[tid*PP + tid] = sum * (1.f/17.f);
    }
    __syncthreads();
    for (int t = tid; t < PP*PP*H2n; t += 256) {
        int h = t & 3, s = (t >> 2) % PP, d = t / (PP*H2n);
        float eav = ea[s*PP + d];
        int ja = h*C2n;
        float acc = 0.f;
        for (int cc = 0; cc < C2n; ++cc) {
            int c = (cc + tid) & (C2n-1);
            float v = lrelu(xl[s*F2 + ja + c] + xr[d*F2 + ja + c] + eav*we[ja + c]);
            acc = fmaf(v, att[ja + c], acc);
        }
        alpha[t] = acc;
    }
    __syncthreads();
    if (tid < PP*H2n) {
        int d = tid >> 2, h = tid & 3;
        int base = d*(PP*H2n) + h;
        float m = -1e30f;
        for (int s = 0; s < PP; ++s) m = fmaxf(m, alpha[base + s*H2n]);
        float sum = 0.f;
        for (int s = 0; s < PP; ++s) sum += __expf(alpha[base + s*H2n] - m);
        float inv = 1.f/(sum + 1e-16f);
        for (int s = 0; s < PP; ++s)
            alpha[base + s*H2n] = __expf(alpha[base + s*H2n] - m) * inv;
    }
    __syncthreads();
    // PV + write + BN2 stats (j = tid fixed; d = iteration index)
    float s_loc = 0.f, q_loc = 0.f;
    for (int o = tid; o < PP*F2; o += 256) {
        int d = o >> 8, j = o & (F2-1), h = j >> 6;
        float acc = bias2[j];
        for (int s = 0; s < PP; ++s)
            acc = fmaf(alpha[d*(PP*H2n) + s*H2n + h], xl[s*F2 + j], acc);
        h2[(size_t)g*(PP*F2) + o] = acc;
        s_loc += acc;
        q_loc = fmaf(acc, acc, q_loc);
    }
    atomicAdd(&sum2[tid], s_loc);
    atomicAdd(&ss2[tid], q_loc);
}

// ================= BN2+lrelu + mean-pool + MLP head, 8 graphs/block =================
__global__ __launch_bounds__(256) void mlp_kernel(
    const float* __restrict__ h2, const float* __restrict__ sc2, const float* __restrict__ sh2,
    const float* __restrict__ Wfc1, const float* __restrict__ bfc1,
    const float* __restrict__ Wfc2, const float* __restrict__ bfc2,
    const float* __restrict__ Wfc3, const float* __restrict__ bfc3,
    float* __restrict__ out)
{
    __shared__ float pooled[8][F2];
    __shared__ float y1[8][512];
    __shared__ float y2[8][128];
    const int g0 = blockIdx.x * 8, tid = threadIdx.x;
    const float scv = sc2[tid], shv = sh2[tid];
    #pragma unroll
    for (int gi = 0; gi < 8; ++gi) {
        float s = 0.f;
        for (int n = 0; n < PP; ++n) {
            float v = fmaf(scv, h2[((size_t)(g0+gi)*PP + n)*F2 + tid], shv);
            s += lrelu(v);
        }
        pooled[gi][tid] = s * (1.f/18.f);
    }
    __syncthreads();
    #pragma unroll
    for (int jo = 0; jo < 2; ++jo) {
        int j = tid + jo*256;
        float acc[8];
        float bv = bfc1[j];
        #pragma unroll
        for (int gi = 0; gi < 8; ++gi) acc[gi] = bv;
        for (int k = 0; k < F2; ++k) {
            float w = Wfc1[k*512 + j];
            #pragma unroll
            for (int gi = 0; gi < 8; ++gi) acc[gi] = fmaf(pooled[gi][k], w, acc[gi]);
        }
        #pragma unroll
        for (int gi = 0; gi < 8; ++gi) y1[gi][j] = lrelu(acc[gi]);
    }
    __syncthreads();
    {
        int j = tid & 127, kh = tid >> 7;
        float acc[8] = {0,0,0,0,0,0,0,0};
        for (int k = kh*256; k < kh*256 + 256; ++k) {
            float w = Wfc2[k*128 + j];
            #pragma unroll
            for (int gi = 0; gi < 8; ++gi) acc[gi] = fmaf(y1[gi][k], w, acc[gi]);
        }
        if (kh == 1) {
            #pragma unroll
            for (int gi = 0; gi < 8; ++gi) pooled[gi][j] = acc[gi];
        }
        __syncthreads();
        if (kh == 0) {
            float w3 = Wfc3[j], bv = bfc2[j];
            #pragma unroll
            for (int gi = 0; gi < 8; ++gi)
                y2[gi][j] = lrelu(acc[gi] + pooled[gi][j] + bv) * w3;
        }
    }
    __syncthreads();
    {
        int gi = tid >> 5, l = tid & 31;
        float p = y2[gi][l] + y2[gi][l+32] + y2[gi][l+64] + y2[gi][l+96];
        p += __shfl_xor(p, 1); p += __shfl_xor(p, 2); p += __shfl_xor(p, 4);
        p += __shfl_xor(p, 8); p += __shfl_xor(p, 16);
        if (l == 0) out[g0 + gi] = p + bfc3[0];
    }
}

extern "C" void kernel_launch(void* const* d_in, const int* in_sizes, int n_in,
                              void* d_out, int out_size, void* d_ws, size_t ws_size,
                              hipStream_t stream)
{
    const float* x     = (const float*)d_in[0];
    const float* eattr = (const float*)d_in[1];
    const float* W1l   = (const float*)d_in[4];
    const float* b1l   = (const float*)d_in[5];
    const float* W1r   = (const float*)d_in[6];
    const float* b1r   = (const float*)d_in[7];
    const float* We1   = (const float*)d_in[8];
    const float* att1  = (const float*)d_in[9];
    const float* bias1 = (const float*)d_in[10];
    const float* W2l   = (const float*)d_in[11];
    const float* b2l   = (const float*)d_in[12];
    const float* W2r   = (const float*)d_in[13];
    const float* b2r   = (const float*)d_in[14];
    const float* We2   = (const float*)d_in[15];
    const float* att2  = (const float*)d_in[16];
    const float* bias2 = (const float*)d_in[17];
    const float* g1    = (const float*)d_in[18];
    const float* be1   = (const float*)d_in[19];
    const float* g2    = (const float*)d_in[20];
    const float* be2   = (const float*)d_in[21];
    const float* Wfc1  = (const float*)d_in[22];
    const float* bfc1  = (const float*)d_in[23];
    const float* Wfc2  = (const float*)d_in[24];
    const float* bfc2  = (const float*)d_in[25];
    const float* Wfc3  = (const float*)d_in[26];
    const float* bfc3  = (const float*)d_in[27];
    float* out = (float*)d_out;

    float* ws = (float*)d_ws;
    float* h1 = ws;                                  // NNODE*128 f32
    float* h2 = h1 + (size_t)NNODE*F1;               // NNODE*256 f32
    float* st = h2 + (size_t)NNODE*F2;               // 1536 f32 stats
    float* biascat = st + 1536;                      // 512 f32
    u16* xlr = (u16*)(biascat + 512);                // NNODE*512 bf16
    u16* wbt = xlr + (size_t)NNODE*F2*2;             // 512*128 bf16

    float* sum1 = st,     *ss1 = st+128, *sc1 = st+256,  *sh1 = st+384;
    float* sum2 = st+512, *ss2 = st+768, *sc2 = st+1024, *sh2 = st+1280;

    prep_w<<<259, 256, 0, stream>>>(W2l, W2r, b2l, b2r, wbt, biascat, st);
    gat1_kernel<<<GG, 256, 0, stream>>>(x, eattr, W1l, b1l, W1r, b1r, We1, att1, bias1, h1, sum1, ss1);
    bnfin<<<1, 128, 0, stream>>>(sum1, ss1, g1, be1, sc1, sh1, F1, 1.f/NNODE);
    gemm2_kernel<<<(NNODE/64)*8, 256, 0, stream>>>(h1, sc1, sh1, wbt, biascat, xlr);
    gat2_attn<<<GG, 256, 0, stream>>>(xlr, eattr, We2, att2, bias2, h2, sum2, ss2);
    bnfin<<<1, 256, 0, stream>>>(sum2, ss2, g2, be2, sc2, sh2, F2, 1.f/NNODE);
    mlp_kernel<<<GG/8, 256, 0, stream>>>(h2, sc2, sh2, Wfc1, bfc1, Wfc2, bfc2, Wfc3, bfc3, out);
}